// Round 6
// baseline (109.902 us; speedup 1.0000x reference)
//
#include <hip/hip_runtime.h>
#include <hip/hip_bf16.h>

#define T_DIM 4096
#define E_DIM 2048
#define D_DIM 256

typedef __attribute__((ext_vector_type(4))) float f32x4;
typedef __attribute__((ext_vector_type(8))) short s16x8;

__device__ __forceinline__ unsigned short f2bf(float f) {
  unsigned int u = __float_as_uint(f);
  unsigned int r = (u + 0x7FFFu + ((u >> 16) & 1u)) >> 16;  // RNE
  return (unsigned short)r;
}
__device__ __forceinline__ float bf2f(unsigned short h) {
  return __uint_as_float(((unsigned int)h) << 16);
}

__device__ __forceinline__ f32x4 mfma16(s16x8 a, s16x8 b, f32x4 c) {
  return __builtin_amdgcn_mfma_f32_16x16x32_bf16(a, b, c, 0, 0, 0);
}

__device__ __forceinline__ void gload_lds16(const void* g, void* l) {
  __builtin_amdgcn_global_load_lds((const __attribute__((address_space(1))) void*)g,
                                   (__attribute__((address_space(3))) void*)l, 16, 0, 0);
}

// ---------------- fused fp32 -> bf16 convert (x, Wq, Wk, Wv in one dispatch) --
__global__ __launch_bounds__(256) void cvt_all(const float* __restrict__ x,
                                               const float* __restrict__ wq,
                                               const float* __restrict__ wk,
                                               const float* __restrict__ wv,
                                               unsigned short* __restrict__ xb,
                                               unsigned short* __restrict__ wb) {
  int blk = blockIdx.x;
  const float* src;
  unsigned short* dst;
  int rel;
  if (blk < 4096)      { src = x;  dst = xb;           rel = blk; }
  else if (blk < 4352) { src = wq; dst = wb;           rel = blk - 4096; }
  else if (blk < 4608) { src = wk; dst = wb + 524288;  rel = blk - 4352; }
  else                 { src = wv; dst = wb + 1048576; rel = blk - 4608; }
  int i = rel * 256 + threadIdx.x;
  float4 a = ((const float4*)src)[i * 2];
  float4 b = ((const float4*)src)[i * 2 + 1];
  uint4 o;
  o.x = (unsigned int)f2bf(a.x) | ((unsigned int)f2bf(a.y) << 16);
  o.y = (unsigned int)f2bf(a.z) | ((unsigned int)f2bf(a.w) << 16);
  o.z = (unsigned int)f2bf(b.x) | ((unsigned int)f2bf(b.y) << 16);
  o.w = (unsigned int)f2bf(b.z) | ((unsigned int)f2bf(b.w) << 16);
  ((uint4*)dst)[i] = o;
}

// ---------------- fused QKV projection GEMM: BM=64 BN=64 BK=128, 16 iters -----
// C[4096,768] = xb @ wb^T. grid = 768 (8 XCD x 96), dbuf DMA, counted vmcnt.
// cols: 0-255 Q, 256-511 K, 512-767 V stored transposed (Vt[256][4096]).
__global__ __launch_bounds__(256, 2) void qkv_gemm(
    const unsigned short* __restrict__ xb, const unsigned short* __restrict__ wb,
    unsigned short* __restrict__ Qg, unsigned short* __restrict__ Kg,
    unsigned short* __restrict__ Vt) {
  __shared__ __align__(16) unsigned short Al[2][64 * 128];  // 2 x 16 KB
  __shared__ __align__(16) unsigned short Bl[2][64 * 128];  // 2 x 16 KB
  int tid = threadIdx.x, wid = tid >> 6, lane = tid & 63;
  int lr = lane & 15, lk = lane >> 4;
  int bi = (int)blockIdx.x;
  int j = (bi & 7) * 96 + (bi >> 3);  // 768 = 8*96 bijective XCD remap
  int mb = j / 12, nb = j % 12;       // consecutive j share mb -> xb panel L2-hot
  int bm0 = mb * 64, bn0 = nb * 64;
  int wm = (wid >> 1) * 32, wn = (wid & 1) * 32;

  f32x4 acc[2][2];
#pragma unroll
  for (int m = 0; m < 2; ++m)
#pragma unroll
    for (int n = 0; n < 2; ++n) acc[m][n] = (f32x4){0.f, 0.f, 0.f, 0.f};

  // A/B tiles 64 rows x 128 k. 1024 chunks(16B) each -> 4+4 per thread = 8 DMA/wave.
#define STAGE_QKV(kt, buf)                                                              \
  {                                                                                     \
    int k0 = (kt)*128;                                                                  \
    _Pragma("unroll") for (int i2 = 0; i2 < 4; ++i2) {                                  \
      int idx = (wid * 4 + i2) * 64 + lane;                                             \
      int row = idx >> 4, g = idx & 15;                                                 \
      gload_lds16(&xb[(size_t)(bm0 + row) * E_DIM + k0 + ((g ^ (row & 7)) << 3)],      \
                  &Al[buf][(size_t)(wid * 4 + i2) * 512]);                              \
      gload_lds16(&wb[(size_t)(bn0 + row) * E_DIM + k0 + ((g ^ (row & 7)) << 3)],      \
                  &Bl[buf][(size_t)(wid * 4 + i2) * 512]);                              \
    }                                                                                   \
  }

  STAGE_QKV(0, 0);
  for (int kt = 0; kt < 16; ++kt) {
    int cur = kt & 1;
    __builtin_amdgcn_s_barrier();  // all waves done reading buf[cur^1]
    if (kt + 1 < 16) {
      STAGE_QKV(kt + 1, cur ^ 1);
      asm volatile("s_waitcnt vmcnt(8)" ::: "memory");  // stage(kt) landed (8 exact)
    } else {
      asm volatile("s_waitcnt vmcnt(0)" ::: "memory");
    }
    __builtin_amdgcn_s_barrier();  // stage(kt) visible block-wide
    s16x8 af[4][2], bfr[4][2];
#pragma unroll
    for (int c = 0; c < 4; ++c) {
#pragma unroll
      for (int m = 0; m < 2; ++m)
        af[c][m] = *(const s16x8*)&Al[cur][(size_t)(wm + m * 16 + lr) * 128 +
                                           (((c * 4 + lk) ^ (lr & 7)) << 3)];
#pragma unroll
      for (int n = 0; n < 2; ++n)
        bfr[c][n] = *(const s16x8*)&Bl[cur][(size_t)(wn + n * 16 + lr) * 128 +
                                            (((c * 4 + lk) ^ (lr & 7)) << 3)];
    }
#pragma unroll
    for (int c = 0; c < 4; ++c)
#pragma unroll
      for (int m = 0; m < 2; ++m)
#pragma unroll
        for (int n = 0; n < 2; ++n) acc[m][n] = mfma16(af[c][m], bfr[c][n], acc[m][n]);
  }

  // epilogue: C layout col=lane&15, row=(lane>>4)*4+reg
#pragma unroll
  for (int m = 0; m < 2; ++m) {
    int grow = bm0 + wm + m * 16 + lk * 4;
#pragma unroll
    for (int n = 0; n < 2; ++n) {
      int gcol = bn0 + wn + n * 16 + lr;
      unsigned short h[4];
#pragma unroll
      for (int r = 0; r < 4; ++r) h[r] = f2bf(acc[m][n][r]);
      if (gcol < 256) {
#pragma unroll
        for (int r = 0; r < 4; ++r) Qg[(size_t)(grow + r) * D_DIM + gcol] = h[r];
      } else if (gcol < 512) {
#pragma unroll
        for (int r = 0; r < 4; ++r) Kg[(size_t)(grow + r) * D_DIM + gcol - 256] = h[r];
      } else {
        uint2 w;
        w.x = (unsigned int)h[0] | ((unsigned int)h[1] << 16);
        w.y = (unsigned int)h[2] | ((unsigned int)h[3] << 16);
        *(uint2*)&Vt[(size_t)(gcol - 512) * T_DIM + grow] = w;
      }
    }
  }
#undef STAGE_QKV
}

// ---------------- flash attention: 8 waves x 32q (256-q tile), EXACTLY 2 iters -
// block j = t*(t+1)+s, t in 0..15, s in 0..2t+1; kv64-tiles {2s, 2s+1}.
// K dbuf 2x32KB, V^T dbuf 2x32KB, P 32KB swizzled (per-wave private) = 160KB LDS.
__global__ __launch_bounds__(512, 2) void attn_kernel(
    const unsigned short* __restrict__ Qg, const unsigned short* __restrict__ Kg,
    const unsigned short* __restrict__ Vt, unsigned short* __restrict__ Opart,
    float* __restrict__ mpart, float* __restrict__ lpart) {
  __shared__ __align__(16) unsigned short Kl[2][64 * 256];  // 2 x 32 KB
  __shared__ __align__(16) unsigned short Vl[2][256 * 64];  // 2 x 32 KB
  __shared__ __align__(16) unsigned short Pl[8 * 32 * 64];  // 32 KB, 16B-granule swz

  int bi = (int)blockIdx.x;
  int j = (bi & 7) * 34 + (bi >> 3);  // 272 = 8*34 bijective XCD remap
  int t = (int)((sqrtf(4.0f * (float)j + 1.0f) - 1.0f) * 0.5f);
  while (t > 0 && t * (t + 1) > j) --t;
  while ((t + 1) * (t + 2) <= j) ++t;
  int s = j - t * (t + 1);  // 0..2t+1

  int tid = threadIdx.x, wid = tid >> 6, lane = tid & 63;
  int lr = lane & 15, lk = lane >> 4;
  int q0w = t * 256 + wid * 32;
  unsigned short* pl = &Pl[wid * 2048];  // 32q x 64k per-wave slice

  // K tile 64x256 (32 granules/row), V^T tile 256x64 (8 granules/row).
  // 2048 chunks each / 512 thr -> 4+4 = 8 DMA per wave.
#define STAGE_KV(jt, buf)                                                            \
  {                                                                                  \
    int kv_ = (jt)*64;                                                               \
    _Pragma("unroll") for (int i2 = 0; i2 < 4; ++i2) {                               \
      int idx = (wid * 4 + i2) * 64 + lane;                                          \
      int row = idx >> 5, g = idx & 31;                                              \
      gload_lds16(&Kg[(size_t)(kv_ + row) * D_DIM + ((g ^ (row & 7)) << 3)],         \
                  &Kl[buf][(size_t)(wid * 4 + i2) * 512]);                           \
    }                                                                                \
    _Pragma("unroll") for (int i2 = 0; i2 < 4; ++i2) {                               \
      int idx = (wid * 4 + i2) * 64 + lane;                                          \
      int d_ = idx >> 3, g = idx & 7;                                                \
      gload_lds16(&Vt[(size_t)d_ * T_DIM + kv_ + ((g ^ (d_ & 7)) << 3)],             \
                  &Vl[buf][(size_t)(wid * 4 + i2) * 512]);                           \
    }                                                                                \
  }

  STAGE_KV(2 * s, 0);  // prologue stage (8 DMA/wave)

  s16x8 qf[2][8];
#pragma unroll
  for (int qb = 0; qb < 2; ++qb)
#pragma unroll
    for (int c = 0; c < 8; ++c)
      qf[qb][c] = *(const s16x8*)&Qg[(size_t)(q0w + qb * 16 + lr) * D_DIM + c * 32 + lk * 8];

  float m_run[2] = {-1e30f, -1e30f}, l_run[2] = {0.f, 0.f};
  f32x4 Oa[2][16];
#pragma unroll
  for (int qb = 0; qb < 2; ++qb)
#pragma unroll
    for (int d = 0; d < 16; ++d) Oa[qb][d] = (f32x4){0.f, 0.f, 0.f, 0.f};
  const float scale = 0.0625f;  // 1/sqrt(256)
  int sw = lr & 7;

#pragma unroll
  for (int n = 0; n < 2; ++n) {
    int jt = 2 * s + n, kv = jt * 64, cur = n;
    __builtin_amdgcn_s_barrier();  // all waves done with buf[cur^1]
    if (n == 0) {
      STAGE_KV(jt + 1, 1);
      // outstanding: qf(16) + stage0(8) + stage1(8) = 32 -> drain 24 oldest
      asm volatile("s_waitcnt vmcnt(8)" ::: "memory");
    } else {
      asm volatile("s_waitcnt vmcnt(0)" ::: "memory");
    }
    __builtin_amdgcn_s_barrier();  // tile n visible block-wide
    const unsigned short* kl = &Kl[cur][0];
    const unsigned short* vl = &Vl[cur][0];

    // ---- QK^T: S^T[key x q], kf shared across both q-frags ----
    f32x4 sa[2][4];
#pragma unroll
    for (int qb = 0; qb < 2; ++qb)
#pragma unroll
      for (int jb = 0; jb < 4; ++jb) sa[qb][jb] = (f32x4){0.f, 0.f, 0.f, 0.f};
#pragma unroll
    for (int jb = 0; jb < 4; ++jb) {
      int rowbase = (jb * 16 + lr) * 256;
#pragma unroll
      for (int c = 0; c < 8; ++c) {
        s16x8 kf = *(const s16x8*)&kl[(size_t)rowbase + (((c * 4 + lk) ^ sw) << 3)];
        sa[0][jb] = mfma16(kf, qf[0][c], sa[0][jb]);
        sa[1][jb] = mfma16(kf, qf[1][c], sa[1][jb]);
      }
    }

    // ---- scale + causal mask + online softmax (per q-frag) ----
    bool needmask = (kv + 63 > q0w);
    float alpha_s[2];
#pragma unroll
    for (int qb = 0; qb < 2; ++qb) {
      int myq = q0w + qb * 16 + lr;
      float tmax = -1e30f;
#pragma unroll
      for (int jb = 0; jb < 4; ++jb) {
#pragma unroll
        for (int r = 0; r < 4; ++r) {
          float v = sa[qb][jb][r] * scale;
          if (needmask && (kv + jb * 16 + lk * 4 + r) > myq) v = -1e30f;
          sa[qb][jb][r] = v;
          tmax = fmaxf(tmax, v);
        }
      }
      tmax = fmaxf(tmax, __shfl_xor(tmax, 16));
      tmax = fmaxf(tmax, __shfl_xor(tmax, 32));
      float m_new = fmaxf(fmaxf(m_run[qb], tmax), -1e29f);  // all-masked safe
      alpha_s[qb] = __expf(m_run[qb] - m_new);
      float psum = 0.f;
      int q = qb * 16 + lr;
#pragma unroll
      for (int jb = 0; jb < 4; ++jb) {
        float p0 = __expf(sa[qb][jb][0] - m_new);
        float p1 = __expf(sa[qb][jb][1] - m_new);
        float p2 = __expf(sa[qb][jb][2] - m_new);
        float p3 = __expf(sa[qb][jb][3] - m_new);
        psum += (p0 + p1) + (p2 + p3);
        uint2 w;
        w.x = (unsigned int)f2bf(p0) | ((unsigned int)f2bf(p1) << 16);
        w.y = (unsigned int)f2bf(p2) | ((unsigned int)f2bf(p3) << 16);
        // P[q][k] with 16B-granule XOR swizzle: granule (jb*2+(lk>>1)) ^ (q&7)
        *(uint2*)&pl[(size_t)q * 64 + (((jb * 2 + (lk >> 1)) ^ sw) << 3) + (lk & 1) * 4] = w;
      }
      psum += __shfl_xor(psum, 16);
      psum += __shfl_xor(psum, 32);
      l_run[qb] = l_run[qb] * alpha_s[qb] + psum;
      m_run[qb] = m_new;
    }

    // ---- rescale O (row q = lk*4+r within each q-frag) ----
    float al[2][4];
#pragma unroll
    for (int qb = 0; qb < 2; ++qb)
#pragma unroll
      for (int r = 0; r < 4; ++r) al[qb][r] = __shfl(alpha_s[qb], lk * 4 + r);
#pragma unroll
    for (int qb = 0; qb < 2; ++qb)
#pragma unroll
      for (int d = 0; d < 16; ++d) {
#pragma unroll
        for (int r = 0; r < 4; ++r) Oa[qb][d][r] *= al[qb][r];
      }

    // ---- PV: P frags (swizzled, per-wave) x V frags (swizzled LDS) ----
    s16x8 pf[2][2];
#pragma unroll
    for (int qb = 0; qb < 2; ++qb)
#pragma unroll
      for (int ks = 0; ks < 2; ++ks)
        pf[qb][ks] = *(const s16x8*)&pl[(size_t)(qb * 16 + lr) * 64 +
                                        (((ks * 4 + lk) ^ sw) << 3)];
#pragma unroll
    for (int d = 0; d < 16; ++d) {
#pragma unroll
      for (int ks = 0; ks < 2; ++ks) {
        s16x8 vf = *(const s16x8*)&vl[(size_t)(d * 16 + lr) * 64 +
                                      (((ks * 4 + lk) ^ sw) << 3)];
        Oa[0][d] = mfma16(pf[0][ks], vf, Oa[0][d]);
        Oa[1][d] = mfma16(pf[1][ks], vf, Oa[1][d]);
      }
    }
  }

  // ---- store partials: Opart[j][256 d][256 q] bf16 ----
#pragma unroll
  for (int d = 0; d < 16; ++d) {
#pragma unroll
    for (int qb = 0; qb < 2; ++qb) {
      unsigned short h[4];
#pragma unroll
      for (int r = 0; r < 4; ++r) h[r] = f2bf(Oa[qb][d][r]);
      uint2 w;
      w.x = (unsigned int)h[0] | ((unsigned int)h[1] << 16);
      w.y = (unsigned int)h[2] | ((unsigned int)h[3] << 16);
      *(uint2*)&Opart[((size_t)j * 256 + d * 16 + lr) * 256 + wid * 32 + qb * 16 + lk * 4] = w;
    }
  }
  if (lk == 0) {
#pragma unroll
    for (int qb = 0; qb < 2; ++qb) {
      mpart[(size_t)j * 256 + wid * 32 + qb * 16 + lr] = m_run[qb];
      lpart[(size_t)j * 256 + wid * 32 + qb * 16 + lr] = l_run[qb];
    }
  }
#undef STAGE_KV
}

// ---------------- merge partials -> final output ------------------------------
// grid = 16 t-tiles x 8 d-groups(32); partials for t are CONTIGUOUS: p = t(t+1)+s.
__global__ __launch_bounds__(256) void merge_kernel(const unsigned short* __restrict__ Opart,
                                                    const float* __restrict__ mpart,
                                                    const float* __restrict__ lpart,
                                                    float* __restrict__ out) {
  __shared__ float trans[256 * 33];
  int blk = blockIdx.x;
  int t = blk >> 3, d0 = (blk & 7) * 32, q0 = t * 256;
  int ql = threadIdx.x;  // q column 0..255
  int base = t * (t + 1), np = 2 * t + 2;

  float M = -1e30f, den = 0.f;
  float acc[32];
#pragma unroll
  for (int k = 0; k < 32; ++k) acc[k] = 0.f;

#pragma unroll 1
  for (int p = 0; p < np; ++p) {
    float mp = mpart[(size_t)(base + p) * 256 + ql];
    float lp = lpart[(size_t)(base + p) * 256 + ql];
    float Mn = fmaxf(M, mp);
    float sc = __expf(M - Mn);
    float w = __expf(mp - Mn);
    den = den * sc + w * lp;
    const unsigned short* op = &Opart[((size_t)(base + p) * 256 + d0) * 256 + ql];
#pragma unroll
    for (int k = 0; k < 32; ++k) acc[k] = acc[k] * sc + w * bf2f(op[(size_t)k * 256]);
    M = Mn;
  }
  float inv = 1.0f / den;
#pragma unroll
  for (int k = 0; k < 32; ++k) trans[ql * 33 + k] = acc[k] * inv;
  __syncthreads();

  // coalesced writes: 32 lanes sweep contiguous d
#pragma unroll
  for (int k = 0; k < 32; ++k) {
    int q = (threadIdx.x >> 5) + 8 * k;
    int dd = threadIdx.x & 31;
    out[(size_t)(q0 + q) * 256 + d0 + dd] = trans[q * 33 + dd];
  }
}

// ---------------- host launch --------------------------------------------------
extern "C" void kernel_launch(void* const* d_in, const int* in_sizes, int n_in,
                              void* d_out, int out_size, void* d_ws, size_t ws_size,
                              hipStream_t stream) {
  const float* x  = (const float*)d_in[0];
  const float* Wq = (const float*)d_in[1];
  const float* Wk = (const float*)d_in[2];
  const float* Wv = (const float*)d_in[3];

  char* ws = (char*)d_ws;
  // workspace layout (bytes):
  //   xb    [4096][2048] bf16 : 16,777,216   @ 0
  //   wb    [768][2048]  bf16 :  3,145,728   @ 16,777,216
  //   Qg    [4096][256]  bf16 :  2,097,152   @ 19,922,944
  //   Kg    [4096][256]  bf16 :  2,097,152   @ 22,020,096
  //   Vt    [256][4096]  bf16 :  2,097,152   @ 24,117,248
  //   Opart [272][256][256] bf16: 35,651,584 @ 26,214,400
  //   mpart [272][256] f32    :    278,528   @ 61,865,984
  //   lpart [272][256] f32    :    278,528   @ 62,144,512   (total ~59.5 MB)
  unsigned short* xb = (unsigned short*)(ws);
  unsigned short* wb = (unsigned short*)(ws + 16777216);
  unsigned short* Qg = (unsigned short*)(ws + 19922944);
  unsigned short* Kg = (unsigned short*)(ws + 22020096);
  unsigned short* Vt = (unsigned short*)(ws + 24117248);
  unsigned short* Opart = (unsigned short*)(ws + 26214400);
  float* mpart = (float*)(ws + 61865984);
  float* lpart = (float*)(ws + 62144512);

  cvt_all<<<4864, 256, 0, stream>>>(x, Wq, Wk, Wv, xb, wb);
  qkv_gemm<<<768, 256, 0, stream>>>(xb, wb, Qg, Kg, Vt);
  attn_kernel<<<272, 512, 0, stream>>>(Qg, Kg, Vt, Opart, mpart, lpart);
  merge_kernel<<<128, 256, 0, stream>>>(Opart, mpart, lpart, (float*)d_out);
}

// Round 7
// 97.899 us; speedup vs baseline: 1.1226x; 1.1226x over previous
//
#include <hip/hip_runtime.h>
#include <hip/hip_bf16.h>

#define T_DIM 4096
#define E_DIM 2048
#define D_DIM 256

typedef __attribute__((ext_vector_type(4))) float f32x4;
typedef __attribute__((ext_vector_type(8))) short s16x8;

__device__ __forceinline__ unsigned short f2bf(float f) {
  unsigned int u = __float_as_uint(f);
  unsigned int r = (u + 0x7FFFu + ((u >> 16) & 1u)) >> 16;  // RNE
  return (unsigned short)r;
}
__device__ __forceinline__ float bf2f(unsigned short h) {
  return __uint_as_float(((unsigned int)h) << 16);
}

__device__ __forceinline__ f32x4 mfma16(s16x8 a, s16x8 b, f32x4 c) {
  return __builtin_amdgcn_mfma_f32_16x16x32_bf16(a, b, c, 0, 0, 0);
}

__device__ __forceinline__ void gload_lds16(const void* g, void* l) {
  __builtin_amdgcn_global_load_lds((const __attribute__((address_space(1))) void*)g,
                                   (__attribute__((address_space(3))) void*)l, 16, 0, 0);
}

// ---------------- fused fp32 -> bf16 convert (x, Wq, Wk, Wv in one dispatch) --
__global__ __launch_bounds__(256) void cvt_all(const float* __restrict__ x,
                                               const float* __restrict__ wq,
                                               const float* __restrict__ wk,
                                               const float* __restrict__ wv,
                                               unsigned short* __restrict__ xb,
                                               unsigned short* __restrict__ wb) {
  int blk = blockIdx.x;
  const float* src;
  unsigned short* dst;
  int rel;
  if (blk < 4096)      { src = x;  dst = xb;           rel = blk; }
  else if (blk < 4352) { src = wq; dst = wb;           rel = blk - 4096; }
  else if (blk < 4608) { src = wk; dst = wb + 524288;  rel = blk - 4352; }
  else                 { src = wv; dst = wb + 1048576; rel = blk - 4608; }
  int i = rel * 256 + threadIdx.x;
  float4 a = ((const float4*)src)[i * 2];
  float4 b = ((const float4*)src)[i * 2 + 1];
  uint4 o;
  o.x = (unsigned int)f2bf(a.x) | ((unsigned int)f2bf(a.y) << 16);
  o.y = (unsigned int)f2bf(a.z) | ((unsigned int)f2bf(a.w) << 16);
  o.z = (unsigned int)f2bf(b.x) | ((unsigned int)f2bf(b.y) << 16);
  o.w = (unsigned int)f2bf(b.z) | ((unsigned int)f2bf(b.w) << 16);
  ((uint4*)dst)[i] = o;
}

// ---------------- fused QKV projection GEMM: BM=128 BN=64 BK=64 ---------------
// C[4096,768] = xb @ wb^T. grid=384, 3 blocks/CU, counted vmcnt(6) dbuf DMA.
// cols: 0-255 Q, 256-511 K, 512-767 V stored transposed (Vt[256][4096]).
__global__ __launch_bounds__(256, 3) void qkv_gemm(
    const unsigned short* __restrict__ xb, const unsigned short* __restrict__ wb,
    unsigned short* __restrict__ Qg, unsigned short* __restrict__ Kg,
    unsigned short* __restrict__ Vt) {
  __shared__ __align__(16) unsigned short Al[2][128 * 64];  // 2 x 16 KB
  __shared__ __align__(16) unsigned short Bl[2][64 * 64];   // 2 x 8 KB
  int tid = threadIdx.x, wid = tid >> 6, lane = tid & 63;
  int lr = lane & 15, lk = lane >> 4;
  int bi_ = (int)blockIdx.x;
  int xcd = bi_ & 7, kk = bi_ >> 3;
  int mb_ = (kk / 12) * 8 + xcd, nb_ = kk % 12;
  int bm0 = mb_ * 128, bn0 = nb_ * 64;
  int wm = (wid >> 1) * 64, wn = (wid & 1) * 32;

  f32x4 acc[4][2];
#pragma unroll
  for (int m = 0; m < 4; ++m)
#pragma unroll
    for (int n = 0; n < 2; ++n) acc[m][n] = (f32x4){0.f, 0.f, 0.f, 0.f};

  // A: 128x64 = 1024 chunks -> 4 DMA/wave; B: 64x64 = 512 chunks -> 2 DMA/wave.
#define STAGE_QKV(kt, buf)                                                              \
  {                                                                                     \
    int k0 = (kt)*64;                                                                   \
    _Pragma("unroll") for (int i2 = 0; i2 < 4; ++i2) {                                  \
      int ci = (wid * 4 + i2) * 64 + lane;                                              \
      int row = ci >> 3, cc = ci & 7;                                                   \
      gload_lds16(&xb[(size_t)(bm0 + row) * E_DIM + k0 + ((cc ^ (row & 7)) << 3)],      \
                  &Al[buf][(size_t)(wid * 4 + i2) * 512]);                              \
    }                                                                                   \
    _Pragma("unroll") for (int i2 = 0; i2 < 2; ++i2) {                                  \
      int ci = (wid * 2 + i2) * 64 + lane;                                              \
      int row = ci >> 3, cc = ci & 7;                                                   \
      gload_lds16(&wb[(size_t)(bn0 + row) * E_DIM + k0 + ((cc ^ (row & 7)) << 3)],      \
                  &Bl[buf][(size_t)(wid * 2 + i2) * 512]);                              \
    }                                                                                   \
  }

  STAGE_QKV(0, 0);
  for (int kt = 0; kt < 32; ++kt) {
    int cur = kt & 1;
    __builtin_amdgcn_s_barrier();  // all waves done reading buf[cur^1]
    if (kt + 1 < 32) {
      STAGE_QKV(kt + 1, cur ^ 1);
      asm volatile("s_waitcnt vmcnt(6)" ::: "memory");  // stage(kt) drained (6 exact)
    } else {
      asm volatile("s_waitcnt vmcnt(0)" ::: "memory");
    }
    __builtin_amdgcn_s_barrier();  // stage(kt) visible block-wide
    s16x8 af[2][4], bfr[2][2];
#pragma unroll
    for (int c = 0; c < 2; ++c) {
#pragma unroll
      for (int m = 0; m < 4; ++m)
        af[c][m] = *(const s16x8*)&Al[cur][(size_t)(wm + m * 16 + lr) * 64 +
                                           (((c * 4 + lk) ^ (lr & 7)) << 3)];
#pragma unroll
      for (int n = 0; n < 2; ++n)
        bfr[c][n] = *(const s16x8*)&Bl[cur][(size_t)(wn + n * 16 + lr) * 64 +
                                            (((c * 4 + lk) ^ (lr & 7)) << 3)];
    }
#pragma unroll
    for (int c = 0; c < 2; ++c)
#pragma unroll
      for (int m = 0; m < 4; ++m)
#pragma unroll
        for (int n = 0; n < 2; ++n) acc[m][n] = mfma16(af[c][m], bfr[c][n], acc[m][n]);
  }

  // epilogue: C layout col=lane&15, row=(lane>>4)*4+reg
#pragma unroll
  for (int m = 0; m < 4; ++m) {
    int grow = bm0 + wm + m * 16 + lk * 4;
#pragma unroll
    for (int n = 0; n < 2; ++n) {
      int gcol = bn0 + wn + n * 16 + lr;
      unsigned short h[4];
#pragma unroll
      for (int r = 0; r < 4; ++r) h[r] = f2bf(acc[m][n][r]);
      if (gcol < 256) {
#pragma unroll
        for (int r = 0; r < 4; ++r) Qg[(size_t)(grow + r) * D_DIM + gcol] = h[r];
      } else if (gcol < 512) {
#pragma unroll
        for (int r = 0; r < 4; ++r) Kg[(size_t)(grow + r) * D_DIM + gcol - 256] = h[r];
      } else {
        uint2 w;
        w.x = (unsigned int)h[0] | ((unsigned int)h[1] << 16);
        w.y = (unsigned int)h[2] | ((unsigned int)h[3] << 16);
        *(uint2*)&Vt[(size_t)(gcol - 512) * T_DIM + grow] = w;
      }
    }
  }
#undef STAGE_QKV
}

// ---------------- flash attention: 8 waves x 16q (128-q tile), 2 iters --------
// block j = t*(t+1)/2 + s, t in 0..31, s in 0..t; kv64-tiles {2s, 2s+1}.
// Per-wave state halved vs R6 (qf 32 VGPR + Oa 64 acc) -> NO scratch spills.
// K dbuf 2x32KB, V^T dbuf 2x32KB, P 16KB per-wave-private = 144KB LDS.
__global__ __launch_bounds__(512, 2) void attn_kernel(
    const unsigned short* __restrict__ Qg, const unsigned short* __restrict__ Kg,
    const unsigned short* __restrict__ Vt, unsigned short* __restrict__ Opart,
    float* __restrict__ mpart, float* __restrict__ lpart) {
  __shared__ __align__(16) unsigned short Kl[2][64 * 256];  // 2 x 32 KB
  __shared__ __align__(16) unsigned short Vl[2][256 * 64];  // 2 x 32 KB
  __shared__ __align__(16) unsigned short Pl[8][16 * 64];   // 16 KB

  int bi = (int)blockIdx.x;
  int j = (bi & 7) * 66 + (bi >> 3);  // 528 = 8*66 bijective XCD remap
  int t = (int)((sqrtf(8.0f * (float)j + 1.0f) - 1.0f) * 0.5f);
  while (t > 0 && t * (t + 1) / 2 > j) --t;
  while ((t + 1) * (t + 2) / 2 <= j) ++t;
  int s = j - t * (t + 1) / 2;  // 0..t

  int tid = threadIdx.x, wid = tid >> 6, lane = tid & 63;
  int lr = lane & 15, lk = lane >> 4;
  int q0w = t * 128 + wid * 16;
  unsigned short* pl = &Pl[wid][0];

  // K tile 64x256 (32 granules/row) and V^T tile 256x64 (8 granules/row):
  // 2048 chunks each / 512 thr -> 4 + 4 = 8 DMA per wave per stage.
#define STAGE_KV(jt, buf)                                                            \
  {                                                                                  \
    int kv_ = (jt)*64;                                                               \
    _Pragma("unroll") for (int i2 = 0; i2 < 4; ++i2) {                               \
      int idx = (wid * 4 + i2) * 64 + lane;                                          \
      int row = idx >> 5, g = idx & 31;                                              \
      gload_lds16(&Kg[(size_t)(kv_ + row) * D_DIM + ((g ^ (row & 7)) << 3)],         \
                  &Kl[buf][(size_t)(wid * 4 + i2) * 512]);                           \
    }                                                                                \
    _Pragma("unroll") for (int i2 = 0; i2 < 4; ++i2) {                               \
      int idx = (wid * 4 + i2) * 64 + lane;                                          \
      int d_ = idx >> 3, g = idx & 7;                                                \
      gload_lds16(&Vt[(size_t)d_ * T_DIM + kv_ + ((g ^ (d_ & 7)) << 3)],             \
                  &Vl[buf][(size_t)(wid * 4 + i2) * 512]);                           \
    }                                                                                \
  }

  STAGE_KV(2 * s, 0);  // prologue stage (8 DMA/wave)

  s16x8 qf[8];
#pragma unroll
  for (int c = 0; c < 8; ++c)
    qf[c] = *(const s16x8*)&Qg[(size_t)(q0w + lr) * D_DIM + c * 32 + lk * 8];

  float m_run = -1e30f, l_run = 0.f;
  f32x4 Oa[16];
#pragma unroll
  for (int d = 0; d < 16; ++d) Oa[d] = (f32x4){0.f, 0.f, 0.f, 0.f};
  const float scale = 0.0625f;  // 1/sqrt(256)
  int sw = lr & 7;

#pragma unroll
  for (int n = 0; n < 2; ++n) {
    int jt = 2 * s + n, kv = jt * 64, cur = n;
    __builtin_amdgcn_s_barrier();  // all waves done with buf[cur^1]
    if (n == 0) {
      STAGE_KV(jt + 1, 1);
      // outstanding: stage0(8)+qf(8)+stage1(8)=24 -> drain 16 oldest, keep 8
      asm volatile("s_waitcnt vmcnt(8)" ::: "memory");
    } else {
      asm volatile("s_waitcnt vmcnt(0)" ::: "memory");
    }
    __builtin_amdgcn_s_barrier();  // tile n visible block-wide
    const unsigned short* kl = &Kl[cur][0];
    const unsigned short* vl = &Vl[cur][0];

    // ---- QK^T: S^T[key x q] = mfma(K, Q); lane: q=lr, key=jb*16+lk*4+r ----
    f32x4 sa[4];
#pragma unroll
    for (int jb = 0; jb < 4; ++jb) sa[jb] = (f32x4){0.f, 0.f, 0.f, 0.f};
#pragma unroll
    for (int jb = 0; jb < 4; ++jb) {
      int rowbase = (jb * 16 + lr) * 256;
#pragma unroll
      for (int c = 0; c < 8; ++c) {
        s16x8 kf = *(const s16x8*)&kl[(size_t)rowbase + (((c * 4 + lk) ^ sw) << 3)];
        sa[jb] = mfma16(kf, qf[c], sa[jb]);
      }
    }

    // ---- scale + causal mask + online softmax ----
    bool needmask = (kv + 63 > q0w);
    int myq = q0w + lr;
    float tmax = -1e30f;
#pragma unroll
    for (int jb = 0; jb < 4; ++jb) {
#pragma unroll
      for (int r = 0; r < 4; ++r) {
        float v = sa[jb][r] * scale;
        if (needmask && (kv + jb * 16 + lk * 4 + r) > myq) v = -1e30f;
        sa[jb][r] = v;
        tmax = fmaxf(tmax, v);
      }
    }
    tmax = fmaxf(tmax, __shfl_xor(tmax, 16));
    tmax = fmaxf(tmax, __shfl_xor(tmax, 32));
    float m_new = fmaxf(fmaxf(m_run, tmax), -1e29f);  // all-masked safe
    float alpha = __expf(m_run - m_new);
    float psum = 0.f;
#pragma unroll
    for (int jb = 0; jb < 4; ++jb) {
      float p0 = __expf(sa[jb][0] - m_new);
      float p1 = __expf(sa[jb][1] - m_new);
      float p2 = __expf(sa[jb][2] - m_new);
      float p3 = __expf(sa[jb][3] - m_new);
      psum += (p0 + p1) + (p2 + p3);
      uint2 w;
      w.x = (unsigned int)f2bf(p0) | ((unsigned int)f2bf(p1) << 16);
      w.y = (unsigned int)f2bf(p2) | ((unsigned int)f2bf(p3) << 16);
      // P[q=lr][key], 16B-granule XOR swizzle: granule (jb*2+(lk>>1)) ^ (lr&7)
      *(uint2*)&pl[(size_t)lr * 64 + (((jb * 2 + (lk >> 1)) ^ sw) << 3) + (lk & 1) * 4] = w;
    }
    psum += __shfl_xor(psum, 16);
    psum += __shfl_xor(psum, 32);
    l_run = l_run * alpha + psum;
    m_run = m_new;

    // ---- rescale O (row q = lk*4+r) ----
    float al[4];
#pragma unroll
    for (int r = 0; r < 4; ++r) al[r] = __shfl(alpha, lk * 4 + r);
#pragma unroll
    for (int d = 0; d < 16; ++d) {
#pragma unroll
      for (int r = 0; r < 4; ++r) Oa[d][r] *= al[r];
    }

    // ---- PV: P frags (swizzled, per-wave) x V frags (swizzled LDS) ----
    s16x8 pf[2];
#pragma unroll
    for (int ks = 0; ks < 2; ++ks)
      pf[ks] = *(const s16x8*)&pl[(size_t)lr * 64 + (((ks * 4 + lk) ^ sw) << 3)];
#pragma unroll
    for (int d = 0; d < 16; ++d) {
#pragma unroll
      for (int ks = 0; ks < 2; ++ks) {
        s16x8 vf = *(const s16x8*)&vl[(size_t)(d * 16 + lr) * 64 +
                                      (((ks * 4 + lk) ^ sw) << 3)];
        Oa[d] = mfma16(pf[ks], vf, Oa[d]);
      }
    }
  }

  // ---- store partials: Opart[j][256 d][128 q] bf16 ----
#pragma unroll
  for (int d = 0; d < 16; ++d) {
    unsigned short h[4];
#pragma unroll
    for (int r = 0; r < 4; ++r) h[r] = f2bf(Oa[d][r]);
    uint2 w;
    w.x = (unsigned int)h[0] | ((unsigned int)h[1] << 16);
    w.y = (unsigned int)h[2] | ((unsigned int)h[3] << 16);
    *(uint2*)&Opart[((size_t)j * 256 + d * 16 + lr) * 128 + wid * 16 + lk * 4] = w;
  }
  if (lk == 0) {
    mpart[(size_t)j * 128 + wid * 16 + lr] = m_run;
    lpart[(size_t)j * 128 + wid * 16 + lr] = l_run;
  }
#undef STAGE_KV
}

// ---------------- merge partials -> final output ------------------------------
// grid = 32 t-tiles x 8 d-groups(32); partials for t contiguous: p = t(t+1)/2+s.
__global__ __launch_bounds__(256) void merge_kernel(const unsigned short* __restrict__ Opart,
                                                    const float* __restrict__ mpart,
                                                    const float* __restrict__ lpart,
                                                    float* __restrict__ out) {
  __shared__ float trans[128 * 33];
  int blk = blockIdx.x;
  int t = blk >> 3, d0 = (blk & 7) * 32, q0 = t * 128;
  int ql = threadIdx.x & 127, dg = threadIdx.x >> 7;  // dg in 0..1
  int base = t * (t + 1) / 2, np = t + 1;

  float M = -1e30f, den = 0.f;
  float acc[16];
#pragma unroll
  for (int k = 0; k < 16; ++k) acc[k] = 0.f;

#pragma unroll 1
  for (int p = 0; p < np; ++p) {
    float mp = mpart[(size_t)(base + p) * 128 + ql];
    float lp = lpart[(size_t)(base + p) * 128 + ql];
    float Mn = fmaxf(M, mp);
    float sc = __expf(M - Mn);
    float w = __expf(mp - Mn);
    den = den * sc + w * lp;
    const unsigned short* op = &Opart[((size_t)(base + p) * 256 + d0 + dg) * 128 + ql];
#pragma unroll
    for (int k = 0; k < 16; ++k) acc[k] = acc[k] * sc + w * bf2f(op[(size_t)(2 * k) * 128]);
    M = Mn;
  }
  float inv = 1.0f / den;
#pragma unroll
  for (int k = 0; k < 16; ++k) trans[ql * 33 + dg + 2 * k] = acc[k] * inv;
  __syncthreads();

  // coalesced writes: 32 lanes sweep contiguous d
#pragma unroll
  for (int k = 0; k < 16; ++k) {
    int q = (threadIdx.x >> 5) + 8 * k;
    int dd = threadIdx.x & 31;
    out[(size_t)(q0 + q) * 256 + d0 + dd] = trans[q * 33 + dd];
  }
}

// ---------------- host launch --------------------------------------------------
extern "C" void kernel_launch(void* const* d_in, const int* in_sizes, int n_in,
                              void* d_out, int out_size, void* d_ws, size_t ws_size,
                              hipStream_t stream) {
  const float* x  = (const float*)d_in[0];
  const float* Wq = (const float*)d_in[1];
  const float* Wk = (const float*)d_in[2];
  const float* Wv = (const float*)d_in[3];

  char* ws = (char*)d_ws;
  // workspace layout (bytes):
  //   xb    [4096][2048] bf16 : 16,777,216   @ 0
  //   wb    [768][2048]  bf16 :  3,145,728   @ 16,777,216
  //   Qg    [4096][256]  bf16 :  2,097,152   @ 19,922,944
  //   Kg    [4096][256]  bf16 :  2,097,152   @ 22,020,096
  //   Vt    [256][4096]  bf16 :  2,097,152   @ 24,117,248
  //   Opart [528][256][128] bf16: 34,603,008 @ 26,214,400
  //   mpart [528][128] f32    :    270,336   @ 60,817,408
  //   lpart [528][128] f32    :    270,336   @ 61,087,744   (total ~61.4 MB)
  unsigned short* xb = (unsigned short*)(ws);
  unsigned short* wb = (unsigned short*)(ws + 16777216);
  unsigned short* Qg = (unsigned short*)(ws + 19922944);
  unsigned short* Kg = (unsigned short*)(ws + 22020096);
  unsigned short* Vt = (unsigned short*)(ws + 24117248);
  unsigned short* Opart = (unsigned short*)(ws + 26214400);
  float* mpart = (float*)(ws + 60817408);
  float* lpart = (float*)(ws + 61087744);

  cvt_all<<<4864, 256, 0, stream>>>(x, Wq, Wk, Wv, xb, wb);
  qkv_gemm<<<384, 256, 0, stream>>>(xb, wb, Qg, Kg, Vt);
  attn_kernel<<<528, 512, 0, stream>>>(Qg, Kg, Vt, Opart, mpart, lpart);
  merge_kernel<<<256, 256, 0, stream>>>(Opart, mpart, lpart, (float*)d_out);
}